// Round 1
// baseline (235.741 us; speedup 1.0000x reference)
//
#include <hip/hip_runtime.h>
#include <math.h>

#define IMG_H 2048
#define IMG_W 2048
#define NB    8
#define BORDER 10
#define REP_THR 0.6f
#define ROWS 16   // output rows per thread

typedef float f32x4 __attribute__((ext_vector_type(4)));

// Each thread computes a 16-row x 4-col output strip (float4 per row).
// Rolling 3-row vertical max window: each of the 18 needed input rows
// (y0-1 .. y0+16) is loaded exactly once -> read amplification 18/16 = 1.125
// (vs 6/4 = 1.5 for the previous 4-row patch version).
//
// Row indices for loads are clamped to [BORDER-1, IMG_H-BORDER] = [9, 2038]:
// rows outside that range only ever feed border-masked outputs, so clamping
// is both a bounds guard (row -1 / row 2048 never touched) and a bandwidth
// saving for the first/last strips. The clamp is wave-uniform (gy is uniform
// within a wave), so no divergence.
//
// Output is written with nontemporal stores: it is never re-read, so keep it
// out of L2/L3 and preserve cache residency for the input halo rows.
//
// Mapping: gx = 4-col group (512), gys = 16-row strip (128), b = image (8).
// gx==0 / gx==511 strips are entirely in the column border -> pure zeros.
__global__ __launch_bounds__(256) void nms_kernel(const float* __restrict__ in,
                                                  float* __restrict__ out) {
    const int tid = blockIdx.x * blockDim.x + threadIdx.x;  // < 8*128*512 = 2^19
    const int gx  = tid & 511;
    const int gys = (tid >> 9) & 127;
    const int b   = tid >> 16;

    const int x4 = gx << 2;    // 0..2044
    const int y0 = gys << 4;   // 0..2032

    const size_t img_off = (size_t)b * IMG_H * IMG_W;
    float* obase = out + img_off + (size_t)y0 * IMG_W + x4;

    // Pure column-border strips: 16 rows of zeros, no loads.
    if (gx == 0 || gx == 511) {
        const f32x4 z = {0.f, 0.f, 0.f, 0.f};
#pragma unroll
        for (int j = 0; j < ROWS; ++j)
            __builtin_nontemporal_store(z, (f32x4*)(obase + (size_t)j * IMG_W));
        return;
    }

    const float* ibase = in + img_off + x4;
    const int rlo = BORDER - 1;        // 9
    const int rhi = IMG_H - BORDER;    // 2038

    // load row r (clamped), produce center vals v and horizontal 3-max h
#define LOADROW(r, v, h) do {                                             \
        int rc_ = (r);                                                    \
        rc_ = rc_ < rlo ? rlo : (rc_ > rhi ? rhi : rc_);                  \
        const float* row_ = ibase + (size_t)rc_ * IMG_W;                  \
        (v) = *(const f32x4*)row_;                                        \
        const float l_ = row_[-1];                                        \
        const float q_ = row_[4];                                         \
        (h)[0] = fmaxf(l_,     fmaxf((v)[0], (v)[1]));                    \
        (h)[1] = fmaxf((v)[0], fmaxf((v)[1], (v)[2]));                    \
        (h)[2] = fmaxf((v)[1], fmaxf((v)[2], (v)[3]));                    \
        (h)[3] = fmaxf((v)[2], fmaxf((v)[3], q_));                        \
    } while (0)

    f32x4 vA, hA, vB, hB;
    LOADROW(y0 - 1, vA, hA);   // vA unused; only its h-max matters
    LOADROW(y0,     vB, hB);
    (void)vA;

    // Column border mask (uniform across the 16 rows)
    const bool bx0 = (x4 + 0 >= BORDER) && (x4 + 0 < IMG_W - BORDER);
    const bool bx1 = (x4 + 1 >= BORDER) && (x4 + 1 < IMG_W - BORDER);
    const bool bx2 = (x4 + 2 >= BORDER) && (x4 + 2 < IMG_W - BORDER);
    const bool bx3 = (x4 + 3 >= BORDER) && (x4 + 3 < IMG_W - BORDER);

#pragma unroll
    for (int j = 0; j < ROWS; ++j) {
        const int y = y0 + j;

        f32x4 vC, hC;
        LOADROW(y + 1, vC, hC);

        f32x4 m;
        m[0] = fmaxf(hA[0], fmaxf(hB[0], hC[0]));
        m[1] = fmaxf(hA[1], fmaxf(hB[1], hC[1]));
        m[2] = fmaxf(hA[2], fmaxf(hB[2], hC[2]));
        m[3] = fmaxf(hA[3], fmaxf(hB[3], hC[3]));

        const bool rowok = (y >= BORDER) && (y < IMG_H - BORDER);

        f32x4 r;
        r[0] = (vB[0] == m[0] && vB[0] >= REP_THR && bx0 && rowok) ? 1.f : 0.f;
        r[1] = (vB[1] == m[1] && vB[1] >= REP_THR && bx1 && rowok) ? 1.f : 0.f;
        r[2] = (vB[2] == m[2] && vB[2] >= REP_THR && bx2 && rowok) ? 1.f : 0.f;
        r[3] = (vB[3] == m[3] && vB[3] >= REP_THR && bx3 && rowok) ? 1.f : 0.f;

        __builtin_nontemporal_store(r, (f32x4*)(obase + (size_t)j * IMG_W));

        // slide the vertical window
        hA = hB;
        vB = vC;
        hB = hC;
    }
#undef LOADROW
}

extern "C" void kernel_launch(void* const* d_in, const int* in_sizes, int n_in,
                              void* d_out, int out_size, void* d_ws, size_t ws_size,
                              hipStream_t stream) {
    const float* in = (const float*)d_in[0];
    float* out = (float*)d_out;
    const int total_threads = NB * (IMG_H / ROWS) * (IMG_W / 4);  // 2^19
    const int block = 256;
    const int grid = total_threads / block;                       // 2048
    nms_kernel<<<grid, block, 0, stream>>>(in, out);
}

// Round 2
// 230.115 us; speedup vs baseline: 1.0244x; 1.0244x over previous
//
#include <hip/hip_runtime.h>
#include <math.h>

#define IMG_H 2048
#define IMG_W 2048
#define NB    8
#define BORDER 10
#define REP_THR 0.6f
#define ROWS 8    // output rows per thread

typedef float f32x4 __attribute__((ext_vector_type(4)));

// Each thread computes an 8-row x 4-col output strip (float4 per row).
// ALL 10 input rows (y0-1 .. y0+8) are loaded into registers UP-FRONT as a
// flat unrolled batch of independent global loads (30 load instructions, ~15KB
// per wave in flight) so HBM latency is covered by memory-level parallelism,
// not just wave count. Round-1's rolling-window version (VGPR=28) showed the
// compiler will NOT software-pipeline a serial row loop: 85µs @ 2.4TB/s,
// latency-bound. Round-0's hoisted-6-row version ran ~61µs. This keeps
// round-0's structure with amplification reduced 1.5x -> 1.25x (10 rows / 8).
//
// Row load indices are clamped to [BORDER-1, IMG_H-BORDER] = [9, 2038]: rows
// outside only feed border-masked outputs, so the clamp is both the bounds
// guard and wave-uniform (no divergence).
//
// Output stores are nontemporal: output is never re-read; keep L2/L3 for the
// input (which is L3-resident across bench iterations - FETCH 77MB < 134MB).
//
// Mapping: gx = 4-col group (512), gys = 8-row strip (256), b = image (8).
__global__ __launch_bounds__(256) void nms_kernel(const float* __restrict__ in,
                                                  float* __restrict__ out) {
    const int tid = blockIdx.x * blockDim.x + threadIdx.x;  // < 8*256*512 = 2^20
    const int gx  = tid & 511;
    const int gys = (tid >> 9) & 255;
    const int b   = tid >> 17;

    const int x4 = gx << 2;    // 0..2044
    const int y0 = gys << 3;   // 0..2040

    const size_t img_off = (size_t)b * IMG_H * IMG_W;
    float* obase = out + img_off + (size_t)y0 * IMG_W + x4;

    // Pure-border strips: column border (gx 0/511) or fully inside the row
    // border (strip 0: rows 0-7; strip 255: rows 2040-2047). Zero, no loads.
    if (gx == 0 || gx == 511 || y0 + ROWS <= BORDER || y0 >= IMG_H - BORDER) {
        const f32x4 z = {0.f, 0.f, 0.f, 0.f};
#pragma unroll
        for (int j = 0; j < ROWS; ++j)
            __builtin_nontemporal_store(z, (f32x4*)(obase + (size_t)j * IMG_W));
        return;
    }

    const float* ibase = in + img_off + x4;

    // ---- Phase 1: issue ALL loads (independent; compiler batches them) ----
    f32x4 v[ROWS + 2];
    float l[ROWS + 2], q[ROWS + 2];
#pragma unroll
    for (int r = 0; r < ROWS + 2; ++r) {
        int rc = y0 - 1 + r;
        rc = rc < (BORDER - 1) ? (BORDER - 1)
           : (rc > (IMG_H - BORDER) ? (IMG_H - BORDER) : rc);
        const float* row = ibase + (size_t)rc * IMG_W;
        v[r] = *(const f32x4*)row;
        l[r] = row[-1];
        q[r] = row[4];
    }

    // ---- Phase 2: horizontal 3-max per row ----
    f32x4 h[ROWS + 2];
#pragma unroll
    for (int r = 0; r < ROWS + 2; ++r) {
        h[r][0] = fmaxf(l[r],    fmaxf(v[r][0], v[r][1]));
        h[r][1] = fmaxf(v[r][0], fmaxf(v[r][1], v[r][2]));
        h[r][2] = fmaxf(v[r][1], fmaxf(v[r][2], v[r][3]));
        h[r][3] = fmaxf(v[r][2], fmaxf(v[r][3], q[r]));
    }

    // Column border mask (uniform across the rows of the strip)
    const bool bx0 = (x4 + 0 >= BORDER) && (x4 + 0 < IMG_W - BORDER);
    const bool bx1 = (x4 + 1 >= BORDER) && (x4 + 1 < IMG_W - BORDER);
    const bool bx2 = (x4 + 2 >= BORDER) && (x4 + 2 < IMG_W - BORDER);
    const bool bx3 = (x4 + 3 >= BORDER) && (x4 + 3 < IMG_W - BORDER);

    // ---- Phase 3: vertical 3-max, compare, store ----
#pragma unroll
    for (int j = 0; j < ROWS; ++j) {
        const int y = y0 + j;
        const bool rowok = (y >= BORDER) && (y < IMG_H - BORDER);

        f32x4 m;
        m[0] = fmaxf(h[j][0], fmaxf(h[j + 1][0], h[j + 2][0]));
        m[1] = fmaxf(h[j][1], fmaxf(h[j + 1][1], h[j + 2][1]));
        m[2] = fmaxf(h[j][2], fmaxf(h[j + 1][2], h[j + 2][2]));
        m[3] = fmaxf(h[j][3], fmaxf(h[j + 1][3], h[j + 2][3]));

        const f32x4 c = v[j + 1];
        f32x4 r;
        r[0] = (c[0] == m[0] && c[0] >= REP_THR && bx0 && rowok) ? 1.f : 0.f;
        r[1] = (c[1] == m[1] && c[1] >= REP_THR && bx1 && rowok) ? 1.f : 0.f;
        r[2] = (c[2] == m[2] && c[2] >= REP_THR && bx2 && rowok) ? 1.f : 0.f;
        r[3] = (c[3] == m[3] && c[3] >= REP_THR && bx3 && rowok) ? 1.f : 0.f;

        __builtin_nontemporal_store(r, (f32x4*)(obase + (size_t)j * IMG_W));
    }
}

extern "C" void kernel_launch(void* const* d_in, const int* in_sizes, int n_in,
                              void* d_out, int out_size, void* d_ws, size_t ws_size,
                              hipStream_t stream) {
    const float* in = (const float*)d_in[0];
    float* out = (float*)d_out;
    const int total_threads = NB * (IMG_H / ROWS) * (IMG_W / 4);  // 2^20
    const int block = 256;
    const int grid = total_threads / block;                       // 4096
    nms_kernel<<<grid, block, 0, stream>>>(in, out);
}

// Round 3
// 229.393 us; speedup vs baseline: 1.0277x; 1.0032x over previous
//
#include <hip/hip_runtime.h>
#include <math.h>

#define IMG_H 2048
#define IMG_W 2048
#define NB    8
#define BORDER 10
#define REP_THR 0.6f
#define ROWS 8    // output rows per thread

typedef float f32x4 __attribute__((ext_vector_type(4)));

// Each thread computes an 8-row x 4-col output strip (float4 per row).
//
// KEY CHANGE vs round 2: round 2's counters showed VGPR_Count=32 — the
// AMDGPU backend's occupancy-first scheduler sank every load to its first
// use, leaving only ~2 loads in flight per wave -> latency-bound at 82us
// (roofline ~45us). Fix:
//   (a) __launch_bounds__(256, 4): request only 4 waves/SIMD -> VGPR budget
//       ~128, so the scheduler stops minimizing pressure to hit 8 waves.
//   (b) __builtin_amdgcn_sched_barrier(0) after the load phase: nothing may
//       cross it, so ALL 30 row loads (10 rows x {float4, left, right}) must
//       issue before any compute -> ~11 KB in flight per wave.
//
// Row load indices are clamped to [BORDER-1, IMG_H-BORDER] = [9, 2038]: rows
// outside only feed border-masked outputs (wave-uniform clamp, no divergence,
// doubles as the bounds guard).
//
// Output stores are nontemporal: output is never re-read; preserve L2/L3
// residency for the input halo (FETCH 85MB < 134MB input confirms L3 reuse).
__global__ __launch_bounds__(256, 4) void nms_kernel(const float* __restrict__ in,
                                                     float* __restrict__ out) {
    const int tid = blockIdx.x * blockDim.x + threadIdx.x;  // < 8*256*512 = 2^20
    const int gx  = tid & 511;
    const int gys = (tid >> 9) & 255;
    const int b   = tid >> 17;

    const int x4 = gx << 2;    // 0..2044
    const int y0 = gys << 3;   // 0..2040

    const size_t img_off = (size_t)b * IMG_H * IMG_W;
    float* obase = out + img_off + (size_t)y0 * IMG_W + x4;

    // Pure-border strips: column border (gx 0/511) or fully inside the row
    // border (strip 0: rows 0-7; strip 255: rows 2040-2047). Zero, no loads.
    if (gx == 0 || gx == 511 || y0 + ROWS <= BORDER || y0 >= IMG_H - BORDER) {
        const f32x4 z = {0.f, 0.f, 0.f, 0.f};
#pragma unroll
        for (int j = 0; j < ROWS; ++j)
            __builtin_nontemporal_store(z, (f32x4*)(obase + (size_t)j * IMG_W));
        return;
    }

    const float* ibase = in + img_off + x4;

    // ---- Phase 1: issue ALL loads; sched_barrier pins them before compute ----
    f32x4 v[ROWS + 2];
    float l[ROWS + 2], q[ROWS + 2];
#pragma unroll
    for (int r = 0; r < ROWS + 2; ++r) {
        int rc = y0 - 1 + r;
        rc = rc < (BORDER - 1) ? (BORDER - 1)
           : (rc > (IMG_H - BORDER) ? (IMG_H - BORDER) : rc);
        const float* row = ibase + (size_t)rc * IMG_W;
        v[r] = *(const f32x4*)row;
        l[r] = row[-1];
        q[r] = row[4];
    }
    __builtin_amdgcn_sched_barrier(0);   // force all loads to issue first

    // ---- Phase 2: horizontal 3-max per row ----
    f32x4 h[ROWS + 2];
#pragma unroll
    for (int r = 0; r < ROWS + 2; ++r) {
        h[r][0] = fmaxf(l[r],    fmaxf(v[r][0], v[r][1]));
        h[r][1] = fmaxf(v[r][0], fmaxf(v[r][1], v[r][2]));
        h[r][2] = fmaxf(v[r][1], fmaxf(v[r][2], v[r][3]));
        h[r][3] = fmaxf(v[r][2], fmaxf(v[r][3], q[r]));
    }

    // Column border mask (uniform across the rows of the strip)
    const bool bx0 = (x4 + 0 >= BORDER) && (x4 + 0 < IMG_W - BORDER);
    const bool bx1 = (x4 + 1 >= BORDER) && (x4 + 1 < IMG_W - BORDER);
    const bool bx2 = (x4 + 2 >= BORDER) && (x4 + 2 < IMG_W - BORDER);
    const bool bx3 = (x4 + 3 >= BORDER) && (x4 + 3 < IMG_W - BORDER);

    // ---- Phase 3: vertical 3-max, compare, store ----
#pragma unroll
    for (int j = 0; j < ROWS; ++j) {
        const int y = y0 + j;
        const bool rowok = (y >= BORDER) && (y < IMG_H - BORDER);

        f32x4 m;
        m[0] = fmaxf(h[j][0], fmaxf(h[j + 1][0], h[j + 2][0]));
        m[1] = fmaxf(h[j][1], fmaxf(h[j + 1][1], h[j + 2][1]));
        m[2] = fmaxf(h[j][2], fmaxf(h[j + 1][2], h[j + 2][2]));
        m[3] = fmaxf(h[j][3], fmaxf(h[j + 1][3], h[j + 2][3]));

        const f32x4 c = v[j + 1];
        f32x4 r;
        r[0] = (c[0] == m[0] && c[0] >= REP_THR && bx0 && rowok) ? 1.f : 0.f;
        r[1] = (c[1] == m[1] && c[1] >= REP_THR && bx1 && rowok) ? 1.f : 0.f;
        r[2] = (c[2] == m[2] && c[2] >= REP_THR && bx2 && rowok) ? 1.f : 0.f;
        r[3] = (c[3] == m[3] && c[3] >= REP_THR && bx3 && rowok) ? 1.f : 0.f;

        __builtin_nontemporal_store(r, (f32x4*)(obase + (size_t)j * IMG_W));
    }
}

extern "C" void kernel_launch(void* const* d_in, const int* in_sizes, int n_in,
                              void* d_out, int out_size, void* d_ws, size_t ws_size,
                              hipStream_t stream) {
    const float* in = (const float*)d_in[0];
    float* out = (float*)d_out;
    const int total_threads = NB * (IMG_H / ROWS) * (IMG_W / 4);  // 2^20
    const int block = 256;
    const int grid = total_threads / block;                       // 4096
    nms_kernel<<<grid, block, 0, stream>>>(in, out);
}